// Round 5
// baseline (699.784 us; speedup 1.0000x reference)
//
#include <hip/hip_runtime.h>
#include <cstdint>

#define NSI   100000
#define NM    100000
#define NINT  500000
#define NEDGE 500000
#define NB_SCAN 489   // ceil(NINT/1024)

// ---------------- workspace layout (float offsets) ----------------
static const long OFF_WSI  = 0;                       // [128][64] cat: cols 0-31 W1l_si2i, 32-63 W1l_si+W1r_si
static const long OFF_WM   = 8192;                    // [128][64] same for m
static const long OFF_WI   = 16384;                   // [64][32] 0.5*(W1r_si2i+W1r_m2i)
static const long OFF_USI  = 18432;                   // [32] W2l_si2i @ wlin
static const long OFF_UM   = 18464;                   // [32]
static const long OFF_V    = 18496;                   // [32] 0.5*(W2r_si2i+W2r_m2i) @ wlin
static const long OFF_C0   = 18528;                   // [1] scalar bias (pad 32)
static const long OFF_BI   = 18560;                   // [32] 0.5*(b1_si2i+b1_m2i)
static const long OFF_PSI  = 18592;                   // [NSI][32] x_si @ W1l_si2i (16B aligned)
static const long OFF_PM   = OFF_PSI + 3200000;
static const long OFF_SSI  = OFF_PM + 3200000;        // [NSI] layer2 scalar per src node
static const long OFF_SM   = OFF_SSI + 100000;
static const long OFF_RI   = OFF_SM + 100000;         // [NINT][32] x_int@Wi + bi
// int region (cast to int*)
static const long OFF_DEG  = OFF_RI + 16000000;       // deg_si, deg_m (2x500K, ZEROED; consumed by fill)
static const long OFF_RP   = OFF_DEG + 1000000;       // rp_si[500001] @ +0, rp_m[500001] @ +500032
static const long OFF_EI   = OFF_RP + 1000064;        // ei_si, ei_m
static const long OFF_BS   = OFF_EI + 1000000;        // block sums 2x512
static const long OFF_END  = OFF_BS + 1024;           // ~25.6M floats = 102 MB

// ---------------- prep: combined weight tensors ----------------
__global__ __launch_bounds__(256) void prep_kernel(
    const float* __restrict__ W1l_si2i, const float* __restrict__ W1l_si, const float* __restrict__ W1r_si,
    const float* __restrict__ W1l_m2i,  const float* __restrict__ W1l_m,  const float* __restrict__ W1r_m,
    const float* __restrict__ W1r_si2i, const float* __restrict__ W1r_m2i,
    const float* __restrict__ b1_si2i,  const float* __restrict__ b1_m2i,
    const float* __restrict__ W2l_si2i, const float* __restrict__ W2l_m2i,
    const float* __restrict__ W2r_si2i, const float* __restrict__ W2r_m2i,
    const float* __restrict__ b2_si2i,  const float* __restrict__ b2_m2i,
    const float* __restrict__ Wlin,     const float* __restrict__ blin,
    float* __restrict__ Wsi, float* __restrict__ Wm, float* __restrict__ Wi, float* __restrict__ bi,
    float* __restrict__ u_si, float* __restrict__ u_m, float* __restrict__ v, float* __restrict__ c0,
    int* __restrict__ rp_si, int* __restrict__ rp_m)
{
    const int tid = threadIdx.x;
    for (int idx = tid; idx < 128 * 64; idx += 256) {
        int k = idx >> 6, c = idx & 63;
        float a, b;
        if (c < 32) { a = W1l_si2i[k * 32 + c];      b = W1l_m2i[k * 32 + c]; }
        else { int cc = c - 32;
               a = W1l_si[k * 32 + cc] + W1r_si[k * 32 + cc];
               b = W1l_m[k * 32 + cc]  + W1r_m[k * 32 + cc]; }
        Wsi[idx] = a; Wm[idx] = b;
    }
    for (int idx = tid; idx < 64 * 32; idx += 256)
        Wi[idx] = 0.5f * (W1r_si2i[idx] + W1r_m2i[idx]);
    if (tid < 32) {
        bi[tid] = 0.5f * (b1_si2i[tid] + b1_m2i[tid]);
        float us = 0.f, um = 0.f, vv = 0.f;
        for (int k = 0; k < 16; ++k) {
            float wl = Wlin[k];
            us += W2l_si2i[tid * 16 + k] * wl;
            um += W2l_m2i[tid * 16 + k] * wl;
            vv += 0.5f * (W2r_si2i[tid * 16 + k] + W2r_m2i[tid * 16 + k]) * wl;
        }
        u_si[tid] = us; u_m[tid] = um; v[tid] = vv;
    }
    if (tid == 0) {
        float c = blin[0];
        for (int k = 0; k < 16; ++k) c += 0.5f * (b2_si2i[k] + b2_m2i[k]) * Wlin[k];
        c0[0] = c;
        rp_si[NINT] = NEDGE;   // CSR sentinels (deg[i] = rp[i+1]-rp[i])
        rp_m[NINT]  = NEDGE;
    }
}

// ---------------- GEMM src types (merged): K=128, 256-row tile, 8x8 per thread ----------------
// grid.y picks type. outputs: P[N][32] (cols 0-31) and s[N] = relu(X@(W1l+W1r)+b).u (cols 32-63)
__global__ __launch_bounds__(256, 3) void gemm_src(
    const float* __restrict__ X_si, const float* __restrict__ X_m,
    const float* __restrict__ Wsi,  const float* __restrict__ Wm,
    const float* __restrict__ b_si, const float* __restrict__ b_m,
    const float* __restrict__ u_si, const float* __restrict__ u_m,
    float* __restrict__ P_si, float* __restrict__ P_m,
    float* __restrict__ s_si, float* __restrict__ s_m, int N)
{
    const int type = blockIdx.y;
    const float* __restrict__ X    = type ? X_m  : X_si;
    const float* __restrict__ Wcat = type ? Wm   : Wsi;
    const float* __restrict__ bias = type ? b_m  : b_si;
    const float* __restrict__ u    = type ? u_m  : u_si;
    float* __restrict__ P     = type ? P_m  : P_si;
    float* __restrict__ s_out = type ? s_m  : s_si;

    __shared__ float xs[256 * 20];   // 16-k slice, pad 20 (80B rows -> uniform banks)
    __shared__ float lw[16 * 64];    // W k-slice
    __shared__ float sp[256 * 5];    // s partials (4 col-groups + pad)
    const int tid = threadIdx.x;
    const long row_base = (long)blockIdx.x * 256;

    const int r0 = tid & 31;         // rows r0 + 32*j, j=0..7
    const int cg = tid >> 5;         // col group 0..7, cols cg*8..cg*8+7
    float acc[8][8];
    #pragma unroll
    for (int j = 0; j < 8; ++j)
        #pragma unroll
        for (int c = 0; c < 8; ++c) acc[j][c] = 0.f;

    for (int s = 0; s < 8; ++s) {    // 8 K-slices of 16
        __syncthreads();
        // stage xs: 256 rows x 4 float4
        #pragma unroll
        for (int i = 0; i < 4; ++i) {
            int idx = tid + i * 256;
            int r = idx >> 2, k4 = idx & 3;
            long rr = row_base + r;
            float4 val = make_float4(0.f, 0.f, 0.f, 0.f);
            if (rr < N) val = ((const float4*)X)[rr * 32 + s * 4 + k4];
            *(float4*)&xs[r * 20 + k4 * 4] = val;
        }
        // stage lw: 16x64 = 256 float4
        ((float4*)lw)[tid] = ((const float4*)Wcat)[s * 256 + tid];
        __syncthreads();

        #pragma unroll
        for (int k = 0; k < 16; k += 4) {
            float4 xr[8];
            #pragma unroll
            for (int j = 0; j < 8; ++j)
                xr[j] = *(const float4*)&xs[(r0 + 32 * j) * 20 + k];
            #pragma unroll
            for (int kk = 0; kk < 4; ++kk) {
                float4 wv0 = *(const float4*)&lw[(k + kk) * 64 + cg * 8];
                float4 wv1 = *(const float4*)&lw[(k + kk) * 64 + cg * 8 + 4];
                #pragma unroll
                for (int j = 0; j < 8; ++j) {
                    float xv = (kk == 0) ? xr[j].x : (kk == 1) ? xr[j].y : (kk == 2) ? xr[j].z : xr[j].w;
                    acc[j][0] = fmaf(xv, wv0.x, acc[j][0]);
                    acc[j][1] = fmaf(xv, wv0.y, acc[j][1]);
                    acc[j][2] = fmaf(xv, wv0.z, acc[j][2]);
                    acc[j][3] = fmaf(xv, wv0.w, acc[j][3]);
                    acc[j][4] = fmaf(xv, wv1.x, acc[j][4]);
                    acc[j][5] = fmaf(xv, wv1.y, acc[j][5]);
                    acc[j][6] = fmaf(xv, wv1.z, acc[j][6]);
                    acc[j][7] = fmaf(xv, wv1.w, acc[j][7]);
                }
            }
        }
    }

    // epilogue
    if (cg < 4) {
        #pragma unroll
        for (int j = 0; j < 8; ++j) {
            long rr = row_base + r0 + 32 * j;
            if (rr < N) {
                *(float4*)&P[rr * 32 + cg * 8]     = make_float4(acc[j][0], acc[j][1], acc[j][2], acc[j][3]);
                *(float4*)&P[rr * 32 + cg * 8 + 4] = make_float4(acc[j][4], acc[j][5], acc[j][6], acc[j][7]);
            }
        }
    } else {
        const int cc = (cg - 4) * 8;   // H-col base 0..24
        float bb[8], uu[8];
        #pragma unroll
        for (int c = 0; c < 8; ++c) { bb[c] = bias[cc + c]; uu[c] = u[cc + c]; }
        #pragma unroll
        for (int j = 0; j < 8; ++j) {
            float part = 0.f;
            #pragma unroll
            for (int c = 0; c < 8; ++c)
                part += fmaxf(acc[j][c] + bb[c], 0.f) * uu[c];
            sp[(r0 + 32 * j) * 5 + (cg - 4)] = part;
        }
    }
    __syncthreads();
    {
        long rr = row_base + tid;
        if (rr < N)
            s_out[rr] = sp[tid * 5 + 0] + sp[tid * 5 + 1] + sp[tid * 5 + 2] + sp[tid * 5 + 3];
    }
}

// ---------------- GEMM int nodes: K=64, M=32, 512-row tile, 8x8 per thread ----------------
__global__ __launch_bounds__(256, 3) void gemm_int(
    const float* __restrict__ X, const float* __restrict__ W,
    const float* __restrict__ bi,
    float* __restrict__ R, int N)
{
    __shared__ float xs[512 * 20];   // 16-k slice
    __shared__ float lw[16 * 32];
    const int tid = threadIdx.x;
    const long row_base = (long)blockIdx.x * 512;

    const int r0 = tid & 63;         // rows r0 + 64*j, j=0..7
    const int cg = tid >> 6;         // col group 0..3 (wave-uniform -> lw broadcast)
    float acc[8][8];
    #pragma unroll
    for (int j = 0; j < 8; ++j)
        #pragma unroll
        for (int c = 0; c < 8; ++c) acc[j][c] = 0.f;

    for (int s = 0; s < 4; ++s) {    // 4 K-slices of 16
        __syncthreads();
        #pragma unroll
        for (int i = 0; i < 8; ++i) {
            int idx = tid + i * 256;
            int r = idx >> 2, k4 = idx & 3;
            long rr = row_base + r;
            float4 val = make_float4(0.f, 0.f, 0.f, 0.f);
            if (rr < N) val = ((const float4*)X)[rr * 16 + s * 4 + k4];
            *(float4*)&xs[r * 20 + k4 * 4] = val;
        }
        if (tid < 128)
            ((float4*)lw)[tid] = ((const float4*)W)[s * 128 + tid];
        __syncthreads();

        #pragma unroll
        for (int k = 0; k < 16; k += 4) {
            float4 xr[8];
            #pragma unroll
            for (int j = 0; j < 8; ++j)
                xr[j] = *(const float4*)&xs[(r0 + 64 * j) * 20 + k];
            #pragma unroll
            for (int kk = 0; kk < 4; ++kk) {
                float4 wv0 = *(const float4*)&lw[(k + kk) * 32 + cg * 8];
                float4 wv1 = *(const float4*)&lw[(k + kk) * 32 + cg * 8 + 4];
                #pragma unroll
                for (int j = 0; j < 8; ++j) {
                    float xv = (kk == 0) ? xr[j].x : (kk == 1) ? xr[j].y : (kk == 2) ? xr[j].z : xr[j].w;
                    acc[j][0] = fmaf(xv, wv0.x, acc[j][0]);
                    acc[j][1] = fmaf(xv, wv0.y, acc[j][1]);
                    acc[j][2] = fmaf(xv, wv0.z, acc[j][2]);
                    acc[j][3] = fmaf(xv, wv0.w, acc[j][3]);
                    acc[j][4] = fmaf(xv, wv1.x, acc[j][4]);
                    acc[j][5] = fmaf(xv, wv1.y, acc[j][5]);
                    acc[j][6] = fmaf(xv, wv1.z, acc[j][6]);
                    acc[j][7] = fmaf(xv, wv1.w, acc[j][7]);
                }
            }
        }
    }

    float bb[8];
    #pragma unroll
    for (int c = 0; c < 8; ++c) bb[c] = bi[cg * 8 + c];
    #pragma unroll
    for (int j = 0; j < 8; ++j) {
        long rr = row_base + r0 + 64 * j;
        if (rr < N) {
            *(float4*)&R[rr * 32 + cg * 8]     = make_float4(acc[j][0] + bb[0], acc[j][1] + bb[1],
                                                             acc[j][2] + bb[2], acc[j][3] + bb[3]);
            *(float4*)&R[rr * 32 + cg * 8 + 4] = make_float4(acc[j][4] + bb[4], acc[j][5] + bb[5],
                                                             acc[j][6] + bb[6], acc[j][7] + bb[7]);
        }
    }
}

// ---------------- CSR build: histogram ----------------
__global__ __launch_bounds__(256) void hist_kernel(
    const int* __restrict__ dst_si, const int* __restrict__ dst_m,
    int* __restrict__ deg_si, int* __restrict__ deg_m)
{
    int e = blockIdx.x * 256 + threadIdx.x;
    if (e >= NEDGE) return;
    if (blockIdx.y == 0) atomicAdd(&deg_si[dst_si[e]], 1);
    else                 atomicAdd(&deg_m[dst_m[e]], 1);
}

// ---------------- CSR build: block-level exclusive scan (1024 elems/block) ----------------
__global__ __launch_bounds__(256) void scan1_kernel(
    const int* __restrict__ deg_si, const int* __restrict__ deg_m,
    int* __restrict__ rp_si, int* __restrict__ rp_m, int* __restrict__ bsum)
{
    const int rel = blockIdx.y;
    const int* deg = rel ? deg_m : deg_si;
    int* rp = rel ? rp_m : rp_si;
    __shared__ int ls[256];
    const int tid = threadIdx.x;
    const int base = blockIdx.x * 1024 + tid * 4;
    int v[4];
    #pragma unroll
    for (int j = 0; j < 4; ++j) v[j] = (base + j < NINT) ? deg[base + j] : 0;
    int tsum = v[0] + v[1] + v[2] + v[3];
    ls[tid] = tsum;
    __syncthreads();
    for (int off = 1; off < 256; off <<= 1) {
        int t = (tid >= off) ? ls[tid - off] : 0;
        __syncthreads();
        ls[tid] += t;
        __syncthreads();
    }
    int run = ls[tid] - tsum;
    #pragma unroll
    for (int j = 0; j < 4; ++j) {
        if (base + j < NINT) rp[base + j] = run;
        run += v[j];
    }
    if (tid == 255) bsum[rel * 512 + blockIdx.x] = ls[255];
}

// ---------------- CSR build: scan of block sums ----------------
__global__ __launch_bounds__(512) void scan2_kernel(int* __restrict__ bsum)
{
    int* bs = bsum + blockIdx.y * 512;
    __shared__ int ls[512];
    const int tid = threadIdx.x;
    int v = (tid < NB_SCAN) ? bs[tid] : 0;
    ls[tid] = v;
    __syncthreads();
    for (int off = 1; off < 512; off <<= 1) {
        int t = (tid >= off) ? ls[tid - off] : 0;
        __syncthreads();
        ls[tid] += t;
        __syncthreads();
    }
    bs[tid] = ls[tid] - v;   // exclusive
}

// ---------------- CSR build: add block offsets ----------------
__global__ __launch_bounds__(256) void scan3_kernel(
    int* __restrict__ rp_si, int* __restrict__ rp_m, const int* __restrict__ bsum)
{
    int i = blockIdx.x * 256 + threadIdx.x;
    if (i >= NINT) return;
    int rel = blockIdx.y;
    int* rp = rel ? rp_m : rp_si;
    rp[i] += bsum[rel * 512 + (i >> 10)];
}

// ---------------- CSR build: bucket fill (deg doubles as down-counting cursor) ----------------
__global__ __launch_bounds__(256) void fill_kernel(
    const int* __restrict__ src_si, const int* __restrict__ dst_si,
    const int* __restrict__ src_m,  const int* __restrict__ dst_m,
    const int* __restrict__ rp_si,  const int* __restrict__ rp_m,
    int* __restrict__ deg_si, int* __restrict__ deg_m,
    int* __restrict__ ei_si,  int* __restrict__ ei_m)
{
    int e = blockIdx.x * 256 + threadIdx.x;
    if (e >= NEDGE) return;
    if (blockIdx.y == 0) {
        int dn = dst_si[e], sn = src_si[e];
        int old = atomicSub(&deg_si[dn], 1);
        ei_si[rp_si[dn] + old - 1] = sn;
    } else {
        int dn = dst_m[e], sn = src_m[e];
        int old = atomicSub(&deg_m[dn], 1);
        ei_m[rp_m[dn] + old - 1] = sn;
    }
}

// ---------------- gather epilogue: 4 features/lane, 8 lanes/node ----------------
__global__ __launch_bounds__(256) void final_gather(
    const float* __restrict__ r_int,
    const float* __restrict__ p_si, const float* __restrict__ p_m,
    const float* __restrict__ s_si, const float* __restrict__ s_m,
    const int* __restrict__ rp_si, const int* __restrict__ ei_si,
    const int* __restrict__ rp_m,  const int* __restrict__ ei_m,
    const float* __restrict__ v, const float* __restrict__ c0,
    float* __restrict__ out)
{
    long gid = (long)blockIdx.x * 256 + threadIdx.x;
    long node = gid >> 3;
    int f4 = threadIdx.x & 7;
    if (node >= NINT) return;

    int rs  = rp_si[node], res = rp_si[node + 1];
    int rm  = rp_m[node],  rem = rp_m[node + 1];
    float4 r  = ((const float4*)r_int)[node * 8 + f4];
    float4 vf = ((const float4*)v)[f4];
    int ds = res - rs, dm = rem - rm;

    int sn_s = (ds > 0) ? ei_si[rs] : 0;
    int sn_m = (dm > 0) ? ei_m[rm] : 0;

    float4 ps = ((const float4*)p_si)[(long)sn_s * 8 + f4];
    float4 pm = ((const float4*)p_m)[(long)sn_m * 8 + f4];
    float qs = s_si[sn_s];
    float qm = s_m[sn_m];

    float msk_s = (ds > 0) ? 1.f : 0.f;
    float msk_m = (dm > 0) ? 1.f : 0.f;
    float4 a_si = make_float4(msk_s * ps.x, msk_s * ps.y, msk_s * ps.z, msk_s * ps.w);
    float4 a_m  = make_float4(msk_m * pm.x, msk_m * pm.y, msk_m * pm.z, msk_m * pm.w);
    float ss_si = msk_s * qs;
    float ss_m  = msk_m * qm;

    for (int e = 1; e < ds; ++e) {
        int sn = ei_si[rs + e];
        float4 p = ((const float4*)p_si)[(long)sn * 8 + f4];
        a_si.x += p.x; a_si.y += p.y; a_si.z += p.z; a_si.w += p.w;
        ss_si += s_si[sn];
    }
    for (int e = 1; e < dm; ++e) {
        int sn = ei_m[rm + e];
        float4 p = ((const float4*)p_m)[(long)sn * 8 + f4];
        a_m.x += p.x; a_m.y += p.y; a_m.z += p.z; a_m.w += p.w;
        ss_m += s_m[sn];
    }

    float wsc = 0.5f / fmaxf((float)ds, 1.0f);
    float wmc = 0.5f / fmaxf((float)dm, 1.0f);

    float h0 = fmaxf(r.x + wsc * a_si.x + wmc * a_m.x, 0.f);
    float h1 = fmaxf(r.y + wsc * a_si.y + wmc * a_m.y, 0.f);
    float h2 = fmaxf(r.z + wsc * a_si.z + wmc * a_m.z, 0.f);
    float h3 = fmaxf(r.w + wsc * a_si.w + wmc * a_m.w, 0.f);
    float t = h0 * vf.x + h1 * vf.y + h2 * vf.z + h3 * vf.w;
    t += __shfl_xor(t, 1);
    t += __shfl_xor(t, 2);
    t += __shfl_xor(t, 4);
    if (f4 == 0)
        out[node] = t + wsc * ss_si + wmc * ss_m + c0[0];
}

extern "C" void kernel_launch(void* const* d_in, const int* in_sizes, int n_in,
                              void* d_out, int out_size, void* d_ws, size_t ws_size,
                              hipStream_t stream)
{
    const float* x_si     = (const float*)d_in[0];
    const float* x_m      = (const float*)d_in[1];
    const float* x_int    = (const float*)d_in[2];
    const float* W1l_si2i = (const float*)d_in[3];
    const float* W1r_si2i = (const float*)d_in[4];
    const float* b1_si2i  = (const float*)d_in[5];
    const float* W1l_m2i  = (const float*)d_in[6];
    const float* W1r_m2i  = (const float*)d_in[7];
    const float* b1_m2i   = (const float*)d_in[8];
    const float* W1l_si   = (const float*)d_in[9];
    const float* W1r_si   = (const float*)d_in[10];
    const float* b1_si    = (const float*)d_in[11];
    const float* W1l_m    = (const float*)d_in[12];
    const float* W1r_m    = (const float*)d_in[13];
    const float* b1_m     = (const float*)d_in[14];
    const float* W2l_si2i = (const float*)d_in[15];
    const float* W2r_si2i = (const float*)d_in[16];
    const float* b2_si2i  = (const float*)d_in[17];
    const float* W2l_m2i  = (const float*)d_in[18];
    const float* W2r_m2i  = (const float*)d_in[19];
    const float* b2_m2i   = (const float*)d_in[20];
    // d_in[21..26] unused (don't reach the readout)
    const float* Wlin     = (const float*)d_in[27];
    const float* blin     = (const float*)d_in[28];
    const int* src_si2i   = (const int*)d_in[29];
    const int* dst_si2i   = (const int*)d_in[30];
    const int* src_m2i    = (const int*)d_in[31];
    const int* dst_m2i    = (const int*)d_in[32];

    float* ws = (float*)d_ws;
    if (ws_size < (size_t)OFF_END * sizeof(float)) return;

    int* deg_si = (int*)(ws + OFF_DEG);
    int* deg_m  = deg_si + 500000;
    int* rp_si  = (int*)(ws + OFF_RP);
    int* rp_m   = rp_si + 500032;
    int* ei_si  = (int*)(ws + OFF_EI);
    int* ei_m   = ei_si + 500000;
    int* bsum   = (int*)(ws + OFF_BS);

    prep_kernel<<<1, 256, 0, stream>>>(
        W1l_si2i, W1l_si, W1r_si, W1l_m2i, W1l_m, W1r_m,
        W1r_si2i, W1r_m2i, b1_si2i, b1_m2i,
        W2l_si2i, W2l_m2i, W2r_si2i, W2r_m2i,
        b2_si2i, b2_m2i, Wlin, blin,
        ws + OFF_WSI, ws + OFF_WM, ws + OFF_WI, ws + OFF_BI,
        ws + OFF_USI, ws + OFF_UM, ws + OFF_V, ws + OFF_C0,
        rp_si, rp_m);

    // zero deg (4 MB)
    hipMemsetAsync(deg_si, 0, 1000000 * sizeof(int), stream);

    // CSR build for both relations
    dim3 egrid((NEDGE + 255) / 256, 2);
    hist_kernel<<<egrid, 256, 0, stream>>>(dst_si2i, dst_m2i, deg_si, deg_m);
    scan1_kernel<<<dim3(NB_SCAN, 2), 256, 0, stream>>>(deg_si, deg_m, rp_si, rp_m, bsum);
    scan2_kernel<<<dim3(1, 2), 512, 0, stream>>>(bsum);
    scan3_kernel<<<dim3((NINT + 255) / 256, 2), 256, 0, stream>>>(rp_si, rp_m, bsum);
    fill_kernel<<<egrid, 256, 0, stream>>>(src_si2i, dst_si2i, src_m2i, dst_m2i,
                                           rp_si, rp_m, deg_si, deg_m, ei_si, ei_m);

    // layer-1 projections: merged src types (8x8 reg tiles), int nodes (8x8 reg tiles)
    gemm_src<<<dim3((NSI + 255) / 256, 2), 256, 0, stream>>>(
        x_si, x_m, ws + OFF_WSI, ws + OFF_WM, b1_si, b1_m,
        ws + OFF_USI, ws + OFF_UM,
        ws + OFF_PSI, ws + OFF_PM, ws + OFF_SSI, ws + OFF_SM, NSI);
    gemm_int<<<(NINT + 511) / 512, 256, 0, stream>>>(x_int, ws + OFF_WI, ws + OFF_BI, ws + OFF_RI, NINT);

    // gather-mean + layer2 + readout (4 features per lane)
    final_gather<<<(NINT * 8) / 256, 256, 0, stream>>>(ws + OFF_RI,
                                                       ws + OFF_PSI, ws + OFF_PM,
                                                       ws + OFF_SSI, ws + OFF_SM,
                                                       rp_si, ei_si,
                                                       rp_m,  ei_m,
                                                       ws + OFF_V, ws + OFF_C0, (float*)d_out);
}